// Round 17
// baseline (225.500 us; speedup 1.0000x reference)
//
#include <hip/hip_runtime.h>
#include <hip/hip_bf16.h>

#define FEATSZ 2048
#define HIDSZ  1024
#define ATTSZ  512
#define BATCH  64
#define FEATN  512

typedef float  f32x4  __attribute__((ext_vector_type(4)));
typedef __bf16 bf16x8 __attribute__((ext_vector_type(8)));

__device__ __forceinline__ unsigned short f2bf(float f) {
    union { float f; unsigned int u; } x; x.f = f;
    unsigned int u = x.u;
    return (unsigned short)((u + 0x7fffu + ((u >> 16) & 1u)) >> 16);
}

// ---------------- K0a: h = key @ wh_w.T + wh_b  (64 x 512) ----------------
__global__ void k_h(const float* __restrict__ key, const float* __restrict__ wh_w,
                    const float* __restrict__ wh_b, float* __restrict__ h) {
    const int b = blockIdx.y;
    const int ac = blockIdx.x;
    const int t = threadIdx.x;         // 256
    const int lane = t & 63, wv = t >> 6;
    float k16[16];
    const float* kb = key + b * HIDSZ;
#pragma unroll
    for (int j = 0; j < 16; ++j) k16[j] = kb[lane + 64 * j];
#pragma unroll 1
    for (int i = 0; i < 16; ++i) {
        int a = ac * 64 + wv * 16 + i;
        const float* wr = wh_w + (size_t)a * HIDSZ;
        float s = 0.f;
#pragma unroll
        for (int j = 0; j < 16; ++j) s += k16[j] * wr[lane + 64 * j];
#pragma unroll
        for (int d = 32; d; d >>= 1) s += __shfl_xor(s, d);
        if (lane == 0) h[b * ATTSZ + a] = s + wh_b[a];
    }
}

// ------- K0b: convert wv_w (512x2048 f32) -> bf16 in MFMA-fragment order -------
// frag (kk, CF) = 1024B at (kk*32+CF)*1024; lane l holds 16B (8 bf16) at +l*16.
__global__ void k_wvcvt(const float* __restrict__ wv_w, unsigned short* __restrict__ wvb) {
    int idx = blockIdx.x * 256 + threadIdx.x;       // < 512*2048
    int a = idx >> 11, k = idx & 2047;
    int CF = a >> 4, c = a & 15, ks = k >> 5, kin = k & 31;
    int lane = c + ((kin >> 3) << 4);
    int dst = ((ks * 32 + CF) * 64 + lane) * 8 + (kin & 7);
    wvb[dst] = f2bf(wv_w[idx]);
}

// ---------------- K1: fused GEMM(feats, wv^T) + tanh·wa -> partial scores -------
// BK=64 long-interval variant of R16: 1024 blocks (XCD-colocated nc-siblings),
// 256 thr = 4 waves (2x2), tile 128r x 128c, 32 kiters x 32 MFMA/wave/barrier.
// A: fp32 glb->reg (1-kiter cover) -> bf16 cvt ONCE -> XOR-swizzled dbuf 2x16KB.
// B: global_load_lds from frag-ordered wvb, ring-2 (2x16KB), 1 kiter ahead,
// counted vmcnt(8) (B prefetch never drained mid-loop). One barrier per kiter.
// LDS 64KB -> 2 blocks/CU.
__global__ __launch_bounds__(256) void k_scores(
        const float* __restrict__ feats, const unsigned short* __restrict__ wvb,
        const float* __restrict__ h, const float* __restrict__ wv_b,
        const float* __restrict__ wa, float* __restrict__ part_sc) {
    __shared__ __align__(16) char smem[65536];   // [0,32K): A dbuf 2x16K ; [32K,64K): B ring 2x16K

    const int t = threadIdx.x, lane = t & 63, w = t >> 6;   // 4 waves
    const int wm = w >> 1, wn = w & 1;
    const int xcd = blockIdx.x & 7, idx = blockIdx.x >> 3;
    const int mb = xcd * 32 + (idx >> 2);       // 0..255 (128-row group)
    const int nc = idx & 3;                     // col quarter
    const int m0 = mb * 128, b = mb >> 2;

    auto Abuf = [&](int i) -> char* { return smem + i * 16384; };
    auto Bbuf = [&](int i) -> char* { return smem + 32768 + i * 16384; };

    // ---- A staging: thread -> row sr = t>>1, k-half shf = t&1 (32 floats each)
    const int sr = t >> 1, shf = t & 1;
    const float* gA = feats + (size_t)(m0 + sr) * FEATSZ + shf * 32;
    int wof[4];
#pragma unroll
    for (int q = 0; q < 4; ++q)
        wof[q] = sr * 128 + (((shf * 4 + q) ^ (sr & 7)) * 16);

    // ---- B staging: wave w covers LDS chunks c = w*4+i (i=0..3) of 16 x 1KB chunks.
    // chunk c holds frag (kk = 2j + (c>>3), CF = nc*8 + (c&7)).
    const char* wvbb = (const char*)wvb;
    unsigned int bsrc[4];
#pragma unroll
    for (int i = 0; i < 4; ++i) {
        int c = w * 4 + i;
        bsrc[i] = (unsigned int)(((c >> 3) * 32 + nc * 8 + (c & 7)) * 1024 + lane * 16);
    }
    const int bdst0 = (w * 4) * 1024 + lane * 16;   // +i*1024

    // ---- A frag read: row = wm*64 + m*16 + l15; chunk = (ks*4+q)^(l15&7); q=lane>>4
    const int l15 = lane & 15, aq = lane >> 4, ax = lane & 7;
    const int arow = (wm * 64 + l15) * 128;
    // ---- B frag read: chunk (ks*8 + wn*4 + cf), per-lane +lane*16
    const int bbase = (wn * 4) * 1024 + lane * 16;

    f32x4 acc[4][4];
#pragma unroll
    for (int m = 0; m < 4; ++m)
#pragma unroll
        for (int cf = 0; cf < 4; ++cf) acc[m][cf] = (f32x4)0.0f;

    f32x4 GA0, GA1, GA2, GA3, GA4, GA5, GA6, GA7;

    auto gloadB = [&](char* dst, int j) {
#pragma unroll
        for (int i = 0; i < 4; ++i)
            __builtin_amdgcn_global_load_lds(
                (const __attribute__((address_space(1))) void*)(wvbb + (size_t)j * 65536 + bsrc[i]),
                (__attribute__((address_space(3))) void*)(dst + bdst0 + i * 1024),
                16, 0, 0);
    };
    auto ldGA = [&](int j) {
        const float* p = gA + j * 64;
        GA0 = *(const f32x4*)(p);      GA1 = *(const f32x4*)(p + 4);
        GA2 = *(const f32x4*)(p + 8);  GA3 = *(const f32x4*)(p + 12);
        GA4 = *(const f32x4*)(p + 16); GA5 = *(const f32x4*)(p + 20);
        GA6 = *(const f32x4*)(p + 24); GA7 = *(const f32x4*)(p + 28);
    };
    auto cvtWrite = [&](char* dst) {
        bf16x8 v0, v1, v2, v3;
        v0[0]=(__bf16)GA0[0]; v0[1]=(__bf16)GA0[1]; v0[2]=(__bf16)GA0[2]; v0[3]=(__bf16)GA0[3];
        v0[4]=(__bf16)GA1[0]; v0[5]=(__bf16)GA1[1]; v0[6]=(__bf16)GA1[2]; v0[7]=(__bf16)GA1[3];
        v1[0]=(__bf16)GA2[0]; v1[1]=(__bf16)GA2[1]; v1[2]=(__bf16)GA2[2]; v1[3]=(__bf16)GA2[3];
        v1[4]=(__bf16)GA3[0]; v1[5]=(__bf16)GA3[1]; v1[6]=(__bf16)GA3[2]; v1[7]=(__bf16)GA3[3];
        v2[0]=(__bf16)GA4[0]; v2[1]=(__bf16)GA4[1]; v2[2]=(__bf16)GA4[2]; v2[3]=(__bf16)GA4[3];
        v2[4]=(__bf16)GA5[0]; v2[5]=(__bf16)GA5[1]; v2[6]=(__bf16)GA5[2]; v2[7]=(__bf16)GA5[3];
        v3[0]=(__bf16)GA6[0]; v3[1]=(__bf16)GA6[1]; v3[2]=(__bf16)GA6[2]; v3[3]=(__bf16)GA6[3];
        v3[4]=(__bf16)GA7[0]; v3[5]=(__bf16)GA7[1]; v3[6]=(__bf16)GA7[2]; v3[7]=(__bf16)GA7[3];
        *(bf16x8*)__builtin_assume_aligned(dst + wof[0], 16) = v0;
        *(bf16x8*)__builtin_assume_aligned(dst + wof[1], 16) = v1;
        *(bf16x8*)__builtin_assume_aligned(dst + wof[2], 16) = v2;
        *(bf16x8*)__builtin_assume_aligned(dst + wof[3], 16) = v3;
    };

    // ---- prologue: GA(0) FIRST (so its drain leaves B(0) in flight), B(0), write, GA(1)
    ldGA(0);
    gloadB(Bbuf(0), 0);
    cvtWrite(Abuf(0));              // compiler waits GA(0) -> vmcnt(4), leaves B(0)
    ldGA(1);
    asm volatile("s_waitcnt vmcnt(8)" ::: "memory");   // drain B(0); GA(1) stays
    asm volatile("s_waitcnt lgkmcnt(0)" ::: "memory");
    __builtin_amdgcn_s_barrier();
    __builtin_amdgcn_sched_barrier(0);

#pragma unroll 1
    for (int j = 0; j < 32; ++j) {
        const char* ar = Abuf(j & 1);
        char*       aw = Abuf((j & 1) ^ 1);
        const char* br = Bbuf(j & 1);
        char*       bw = Bbuf((j & 1) ^ 1);
        // 1. B prefetch next kiter (4 instrs; never drained until end-of-kiter count)
        if (j < 31) gloadB(bw, j + 1);
        // 2. MFMA: two ks halves, 16 each (frag reads inline)
#pragma unroll
        for (int ks = 0; ks < 2; ++ks) {
            bf16x8 BF[4], AF[4];
#pragma unroll
            for (int cf = 0; cf < 4; ++cf)
                BF[cf] = *(const bf16x8*)__builtin_assume_aligned(br + (ks * 8) * 1024 + bbase + cf * 1024, 16);
#pragma unroll
            for (int m = 0; m < 4; ++m)
                AF[m] = *(const bf16x8*)__builtin_assume_aligned(ar + arow + m * 2048 + (((ks * 4 + aq) ^ ax) * 16), 16);
            __builtin_amdgcn_s_setprio(1);
#pragma unroll
            for (int m = 0; m < 4; ++m)
#pragma unroll
                for (int cf = 0; cf < 4; ++cf)
                    acc[m][cf] = __builtin_amdgcn_mfma_f32_16x16x32_bf16(AF[m], BF[cf], acc[m][cf], 0, 0, 0);
            __builtin_amdgcn_s_setprio(0);
        }
        // 3. write A tile j+1 (GA loaded last kiter; compiler waits vmcnt leaving B(j+1))
        if (j < 31) cvtWrite(aw);
        // 4. load GA tile j+2
        if (j < 30) ldGA(j + 2);
        // 5. counted wait: drain B(j+1) (leave GA(j+2) x8); one barrier
        if (j < 30)      asm volatile("s_waitcnt vmcnt(8)" ::: "memory");
        else             asm volatile("s_waitcnt vmcnt(0)" ::: "memory");
        asm volatile("s_waitcnt lgkmcnt(0)" ::: "memory");
        __builtin_amdgcn_s_barrier();
        __builtin_amdgcn_sched_barrier(0);
    }

    // ---- epilogue: partial score over this block's 128 cols (nc quarter)
    const int c16 = lane & 15, q4 = lane >> 4;
    float hreg[4], wreg[4];
#pragma unroll
    for (int cf = 0; cf < 4; ++cf) {
        int a = nc * 128 + wn * 64 + cf * 16 + c16;
        hreg[cf] = h[b * ATTSZ + a] + wv_b[a];
        wreg[cf] = wa[a];
    }
    float pv[4][4];
#pragma unroll
    for (int m = 0; m < 4; ++m)
#pragma unroll
        for (int jr = 0; jr < 4; ++jr) pv[m][jr] = 0.f;
#pragma unroll
    for (int m = 0; m < 4; ++m)
#pragma unroll
        for (int cf = 0; cf < 4; ++cf)
#pragma unroll
            for (int jr = 0; jr < 4; ++jr)
                pv[m][jr] += tanhf(acc[m][cf][jr] + hreg[cf]) * wreg[cf];
#pragma unroll
    for (int m = 0; m < 4; ++m)
#pragma unroll
        for (int jr = 0; jr < 4; ++jr) {
            float v = pv[m][jr];
            v += __shfl_xor(v, 1); v += __shfl_xor(v, 2);
            v += __shfl_xor(v, 4); v += __shfl_xor(v, 8);
            pv[m][jr] = v;
        }
    float* scp = (float*)smem;      // alias (loop ended with barrier)
    __builtin_amdgcn_s_barrier();
    if (c16 == 0) {
#pragma unroll
        for (int m = 0; m < 4; ++m)
#pragma unroll
            for (int jr = 0; jr < 4; ++jr)
                scp[wn * 128 + wm * 64 + m * 16 + q4 * 4 + jr] = pv[m][jr];
    }
    __syncthreads();
    if (t < 128)
        part_sc[(size_t)nc * (BATCH * FEATN) + m0 + t] = scp[t] + scp[128 + t];
}

// ---------------- K2: softmax over N=512 per batch (sums 4 col-partials) --------
__global__ void k_softmax(const float* __restrict__ part_sc, float* __restrict__ alpha) {
    __shared__ float red[16];
    const int b = blockIdx.x, t = threadIdx.x;     // 512 threads
    const int lane = t & 63, w = t >> 6;
    const int r = b * FEATN + t;
    float s = part_sc[r] + part_sc[BATCH * FEATN + r]
            + part_sc[2 * BATCH * FEATN + r] + part_sc[3 * BATCH * FEATN + r];
    float m = s;
#pragma unroll
    for (int d = 32; d; d >>= 1) m = fmaxf(m, __shfl_xor(m, d));
    if (lane == 0) red[w] = m;
    __syncthreads();
    if (t == 0) {
        float mm = red[0];
        for (int i = 1; i < 8; ++i) mm = fmaxf(mm, red[i]);
        red[8] = mm;
    }
    __syncthreads();
    float e = __expf(s - red[8]);
    float sum = e;
#pragma unroll
    for (int d = 32; d; d >>= 1) sum += __shfl_xor(sum, d);
    if (lane == 0) red[w] = sum;
    __syncthreads();
    if (t == 0) {
        float ss = 0.f;
        for (int i = 0; i < 8; ++i) ss += red[i];
        red[9] = 1.0f / ss;
    }
    __syncthreads();
    alpha[b * FEATN + t] = e * red[9];
}

// ---------------- K3a: partial att_feats over n-slices ----------------
__global__ void k_att_part(const float* __restrict__ feats, const float* __restrict__ alpha,
                           float* __restrict__ part) {
    const int b = blockIdx.x, fc = blockIdx.y, ns = blockIdx.z, t = threadIdx.x;
    const int f0 = fc * 1024 + t * 4;
    const float* fp = feats + (size_t)(b * FEATN + ns * 128) * FEATSZ + f0;
    const float* al = alpha + b * FEATN + ns * 128;
    float4 acc = {0.f, 0.f, 0.f, 0.f};
#pragma unroll 4
    for (int i = 0; i < 128; ++i) {
        float a = al[i];
        float4 v = *(const float4*)(fp + (size_t)i * FEATSZ);
        acc.x += a * v.x; acc.y += a * v.y; acc.z += a * v.z; acc.w += a * v.w;
    }
    *(float4*)(part + ((size_t)ns * BATCH + b) * FEATSZ + f0) = acc;
}

// ---------------- K3b: reduce 4 partials -> att_feats ----------------
__global__ void k_att_red(const float* __restrict__ part, float* __restrict__ out) {
    const int idx = (blockIdx.x * 256 + threadIdx.x) * 4;   // < 131072
    float4 s = *(const float4*)(part + idx);
#pragma unroll
    for (int z = 1; z < 4; ++z) {
        float4 v = *(const float4*)(part + (size_t)z * (BATCH * FEATSZ) + idx);
        s.x += v.x; s.y += v.y; s.z += v.z; s.w += v.w;
    }
    *(float4*)(out + idx) = s;
}

extern "C" void kernel_launch(void* const* d_in, const int* in_sizes, int n_in,
                              void* d_out, int out_size, void* d_ws, size_t ws_size,
                              hipStream_t stream) {
    const float* feats = (const float*)d_in[0];
    const float* key   = (const float*)d_in[1];
    const float* wh_w  = (const float*)d_in[2];
    const float* wh_b  = (const float*)d_in[3];
    const float* wv_w  = (const float*)d_in[4];
    const float* wv_b  = (const float*)d_in[5];
    const float* wa_w  = (const float*)d_in[6];

    float* out_att   = (float*)d_out;                 // 64*2048
    float* out_alpha = out_att + BATCH * FEATSZ;      // 64*512

    char* ws = (char*)d_ws;
    float* h            = (float*)(ws);               // 128 KB
    float* part_sc      = (float*)(ws + 131072);      // 4 x 128 KB = 512 KB
    unsigned short* wvb = (unsigned short*)(ws + 655360);  // 2 MB
    float* part         = (float*)(ws + 655360);      // 2 MB (reuses wvb after K1)

    hipLaunchKernelGGL(k_h,        dim3(8, 64),    dim3(256), 0, stream, key, wh_w, wh_b, h);
    hipLaunchKernelGGL(k_wvcvt,    dim3(4096),     dim3(256), 0, stream, wv_w, wvb);
    hipLaunchKernelGGL(k_scores,   dim3(1024),     dim3(256), 0, stream, feats, wvb, h, wv_b, wa_w, part_sc);
    hipLaunchKernelGGL(k_softmax,  dim3(64),       dim3(512), 0, stream, part_sc, out_alpha);
    hipLaunchKernelGGL(k_att_part, dim3(64, 2, 4), dim3(256), 0, stream, feats, out_alpha, part);
    hipLaunchKernelGGL(k_att_red,  dim3(128),      dim3(256), 0, stream, part, out_att);
}

// Round 18
// 161.570 us; speedup vs baseline: 1.3957x; 1.3957x over previous
//
#include <hip/hip_runtime.h>
#include <hip/hip_bf16.h>

#define FEATSZ 2048
#define HIDSZ  1024
#define ATTSZ  512
#define BATCH  64
#define FEATN  512

typedef float  f32x4  __attribute__((ext_vector_type(4)));
typedef __bf16 bf16x8 __attribute__((ext_vector_type(8)));

__device__ __forceinline__ unsigned short f2bf(float f) {
    union { float f; unsigned int u; } x; x.f = f;
    unsigned int u = x.u;
    return (unsigned short)((u + 0x7fffu + ((u >> 16) & 1u)) >> 16);
}

// ---------------- K0a: h = key @ wh_w.T + wh_b  (64 x 512) ----------------
__global__ void k_h(const float* __restrict__ key, const float* __restrict__ wh_w,
                    const float* __restrict__ wh_b, float* __restrict__ h) {
    const int b = blockIdx.y;
    const int ac = blockIdx.x;
    const int t = threadIdx.x;         // 256
    const int lane = t & 63, wv = t >> 6;
    float k16[16];
    const float* kb = key + b * HIDSZ;
#pragma unroll
    for (int j = 0; j < 16; ++j) k16[j] = kb[lane + 64 * j];
#pragma unroll 1
    for (int i = 0; i < 16; ++i) {
        int a = ac * 64 + wv * 16 + i;
        const float* wr = wh_w + (size_t)a * HIDSZ;
        float s = 0.f;
#pragma unroll
        for (int j = 0; j < 16; ++j) s += k16[j] * wr[lane + 64 * j];
#pragma unroll
        for (int d = 32; d; d >>= 1) s += __shfl_xor(s, d);
        if (lane == 0) h[b * ATTSZ + a] = s + wh_b[a];
    }
}

// ------- K0b: convert wv_w (512x2048 f32) -> bf16 in MFMA-fragment order -------
// frag (kk, CF) = 1024B at (kk*32+CF)*1024; lane l holds 16B (8 bf16) at +l*16.
__global__ void k_wvcvt(const float* __restrict__ wv_w, unsigned short* __restrict__ wvb) {
    int idx = blockIdx.x * 256 + threadIdx.x;       // < 512*2048
    int a = idx >> 11, k = idx & 2047;
    int CF = a >> 4, c = a & 15, ks = k >> 5, kin = k & 31;
    int lane = c + ((kin >> 3) << 4);
    int dst = ((ks * 32 + CF) * 64 + lane) * 8 + (kin & 7);
    wvb[dst] = f2bf(wv_w[idx]);
}

// ---------------- K1: fused GEMM(feats, wv^T) + tanh·wa -> scores ----------------
// 256 blocks (1/CU), 8 waves. BM=128 x BN=512(full) x BK=32, 64 K-steps.
// A: bf16 in LDS (4 x 8KB bufs), reg-staged 2 steps ahead (glb->cvt->swizzled
// ds_write); cvt happens ONCE per element at stage, not per MFMA use.
// B: L2-resident frag-ordered wvb, 1-step reg ping-pong (named BX/BY).
// ONE lgkmcnt(0)+s_barrier per K-step; NO vmcnt drain anywhere in the loop
// (global->reg waits are wave-private, compiler-tracked, 1-2 steps of cover).
__global__ __launch_bounds__(512) void k_scores(
        const float* __restrict__ feats, const unsigned short* __restrict__ wvb,
        const float* __restrict__ h, const float* __restrict__ wv_b,
        const float* __restrict__ wa, float* __restrict__ scores) {
    __shared__ __align__(16) char Abuf[4][8192];   // [buf][128 rows][32 k] bf16, swizzled
    __shared__ float scp[8][128];
    const int t = threadIdx.x, lane = t & 63, w = t >> 6;
    const int m0 = blockIdx.x * 128, b = blockIdx.x >> 2;

    // ---- staging map: thread t -> row = t>>2, logical 16B chunk sq = t&3 (k = sq*8..)
    // swizzle: phys_chunk = sq ^ ((row>>1)&3)  -> write & read both 2-way max (free)
    const int srow = t >> 2, sq = t & 3;
    const float* gsrc = feats + (size_t)(m0 + srow) * FEATSZ + sq * 8;
    const int wboff = srow * 64 + ((sq ^ ((t >> 3) & 3)) * 16);   // byte offset in buf

    // ---- A frag read addr: frag m: row = m*16+(lane&15), chunk q=lane>>4,
    //      phys = q ^ ((lane>>1)&3)  (row>>1 & 3 == lane>>1 & 3 for bits<4)
    const int rbase = (lane & 15) * 64 + (((lane >> 4) ^ ((lane >> 1) & 3)) * 16);

    // ---- B: wave w covers cols w*64..+64 -> CF = w*4+cf; frag (kk,CF) at +(kk*32+CF)*512
    const unsigned short* wb = wvb + (size_t)(w * 4) * 512 + lane * 8;

    f32x4 acc[8][4];
#pragma unroll
    for (int m = 0; m < 8; ++m)
#pragma unroll
        for (int cf = 0; cf < 4; ++cf) acc[m][cf] = (f32x4)0.0f;

    f32x4 GA0, GA1, GB0, GB1;      // named A-staging regs (even/odd tiles)
    bf16x8 BX[4], BY[4];           // named B ping-pong (even/odd tiles)

    auto loadBX = [&](int tile) {
#pragma unroll
        for (int cf = 0; cf < 4; ++cf) BX[cf] = *(const bf16x8*)(wb + (size_t)(tile * 32 + cf) * 512);
    };
    auto loadBY = [&](int tile) {
#pragma unroll
        for (int cf = 0; cf < 4; ++cf) BY[cf] = *(const bf16x8*)(wb + (size_t)(tile * 32 + cf) * 512);
    };
    auto writeA = [&](f32x4 r0, f32x4 r1, int tile) {
        bf16x8 v;
        v[0] = (__bf16)r0[0]; v[1] = (__bf16)r0[1]; v[2] = (__bf16)r0[2]; v[3] = (__bf16)r0[3];
        v[4] = (__bf16)r1[0]; v[5] = (__bf16)r1[1]; v[6] = (__bf16)r1[2]; v[7] = (__bf16)r1[3];
        *(bf16x8*)__builtin_assume_aligned(&Abuf[tile & 3][0] + wboff, 16) = v;
    };
    auto bar = [&]() {
        asm volatile("s_waitcnt lgkmcnt(0)" ::: "memory");
        __builtin_amdgcn_s_barrier();
        __builtin_amdgcn_sched_barrier(0);
    };

    // ---- prologue: tiles 0,1 in regs; B(0); write tile 0; barrier
    {
        const float* p0 = gsrc;
        GA0 = *(const f32x4*)p0;        GA1 = *(const f32x4*)(p0 + 4);
        const float* p1 = gsrc + 32;
        GB0 = *(const f32x4*)p1;        GB1 = *(const f32x4*)(p1 + 4);
        loadBX(0);
        writeA(GA0, GA1, 0);
        bar();
    }

#pragma unroll 1
    for (int jj = 0; jj < 32; ++jj) {
        const int j = jj * 2;
        // ---- even step j: compute tile j (BX); write tile j+1 (from GB);
        //      issue tile j+2 -> GA; load B(j+1) -> BY
        if (j <= 61) {
            const float* p = gsrc + (j + 2) * 32;
            GA0 = *(const f32x4*)p; GA1 = *(const f32x4*)(p + 4);
        }
        loadBY(j + 1);
        writeA(GB0, GB1, j + 1);
        {
            const char* ab = &Abuf[j & 3][0];
            __builtin_amdgcn_s_setprio(1);
#pragma unroll
            for (int m = 0; m < 8; ++m) {
                bf16x8 a = *(const bf16x8*)__builtin_assume_aligned(ab + m * 1024 + rbase, 16);
#pragma unroll
                for (int cf = 0; cf < 4; ++cf)
                    acc[m][cf] = __builtin_amdgcn_mfma_f32_16x16x32_bf16(a, BX[cf], acc[m][cf], 0, 0, 0);
            }
            __builtin_amdgcn_s_setprio(0);
        }
        bar();
        // ---- odd step j+1: compute tile j+1 (BY); write tile j+2 (from GA);
        //      issue tile j+3 -> GB; load B(j+2) -> BX
        const int j1 = j + 1;
        if (j1 <= 61) {
            const float* p = gsrc + (j1 + 2) * 32;
            GB0 = *(const f32x4*)p; GB1 = *(const f32x4*)(p + 4);
        }
        if (j1 <= 62) loadBX(j1 + 1);
        if (j1 <= 62) writeA(GA0, GA1, j1 + 1);
        {
            const char* ab = &Abuf[j1 & 3][0];
            __builtin_amdgcn_s_setprio(1);
#pragma unroll
            for (int m = 0; m < 8; ++m) {
                bf16x8 a = *(const bf16x8*)__builtin_assume_aligned(ab + m * 1024 + rbase, 16);
#pragma unroll
                for (int cf = 0; cf < 4; ++cf)
                    acc[m][cf] = __builtin_amdgcn_mfma_f32_16x16x32_bf16(a, BY[cf], acc[m][cf], 0, 0, 0);
            }
            __builtin_amdgcn_s_setprio(0);
        }
        bar();
    }

    // ---- epilogue: p[row] = sum_a tanh(acc + h[b,a] + wv_b[a]) * wa[a]
    const int c16 = lane & 15, q4 = lane >> 4;
    float hreg[4], wreg[4];
#pragma unroll
    for (int cf = 0; cf < 4; ++cf) {
        int a = w * 64 + cf * 16 + c16;
        hreg[cf] = h[b * ATTSZ + a] + wv_b[a];
        wreg[cf] = wa[a];
    }
    float pv[8][4];
#pragma unroll
    for (int m = 0; m < 8; ++m)
#pragma unroll
        for (int jr = 0; jr < 4; ++jr) pv[m][jr] = 0.f;
#pragma unroll
    for (int m = 0; m < 8; ++m)
#pragma unroll
        for (int cf = 0; cf < 4; ++cf)
#pragma unroll
            for (int jr = 0; jr < 4; ++jr)
                pv[m][jr] += tanhf(acc[m][cf][jr] + hreg[cf]) * wreg[cf];
#pragma unroll
    for (int m = 0; m < 8; ++m)
#pragma unroll
        for (int jr = 0; jr < 4; ++jr) {
            float v = pv[m][jr];
            v += __shfl_xor(v, 1); v += __shfl_xor(v, 2);
            v += __shfl_xor(v, 4); v += __shfl_xor(v, 8);
            pv[m][jr] = v;
        }
    if (c16 == 0) {
#pragma unroll
        for (int m = 0; m < 8; ++m)
#pragma unroll
            for (int jr = 0; jr < 4; ++jr)
                scp[w][m * 16 + q4 * 4 + jr] = pv[m][jr];
    }
    __syncthreads();
    if (t < 128) {
        float s = 0.f;
#pragma unroll
        for (int ww = 0; ww < 8; ++ww) s += scp[ww][t];
        scores[m0 + t] = s;
    }
}

// ---------------- K2: softmax over N=512 per batch ----------------
__global__ void k_softmax(const float* __restrict__ scores, float* __restrict__ alpha) {
    __shared__ float red[16];
    const int b = blockIdx.x, t = threadIdx.x;     // 512 threads
    const int lane = t & 63, w = t >> 6;
    float s = scores[b * FEATN + t];
    float m = s;
#pragma unroll
    for (int d = 32; d; d >>= 1) m = fmaxf(m, __shfl_xor(m, d));
    if (lane == 0) red[w] = m;
    __syncthreads();
    if (t == 0) {
        float mm = red[0];
        for (int i = 1; i < 8; ++i) mm = fmaxf(mm, red[i]);
        red[8] = mm;
    }
    __syncthreads();
    float e = __expf(s - red[8]);
    float sum = e;
#pragma unroll
    for (int d = 32; d; d >>= 1) sum += __shfl_xor(sum, d);
    if (lane == 0) red[w] = sum;
    __syncthreads();
    if (t == 0) {
        float ss = 0.f;
        for (int i = 0; i < 8; ++i) ss += red[i];
        red[9] = 1.0f / ss;
    }
    __syncthreads();
    alpha[b * FEATN + t] = e * red[9];
}

// ---------------- K3a: partial att_feats over n-slices ----------------
__global__ void k_att_part(const float* __restrict__ feats, const float* __restrict__ alpha,
                           float* __restrict__ part) {
    const int b = blockIdx.x, fc = blockIdx.y, ns = blockIdx.z, t = threadIdx.x;
    const int f0 = fc * 1024 + t * 4;
    const float* fp = feats + (size_t)(b * FEATN + ns * 128) * FEATSZ + f0;
    const float* al = alpha + b * FEATN + ns * 128;
    float4 acc = {0.f, 0.f, 0.f, 0.f};
#pragma unroll 4
    for (int i = 0; i < 128; ++i) {
        float a = al[i];
        float4 v = *(const float4*)(fp + (size_t)i * FEATSZ);
        acc.x += a * v.x; acc.y += a * v.y; acc.z += a * v.z; acc.w += a * v.w;
    }
    *(float4*)(part + ((size_t)ns * BATCH + b) * FEATSZ + f0) = acc;
}

// ---------------- K3b: reduce 4 partials -> att_feats ----------------
__global__ void k_att_red(const float* __restrict__ part, float* __restrict__ out) {
    const int idx = (blockIdx.x * 256 + threadIdx.x) * 4;   // < 131072
    float4 s = *(const float4*)(part + idx);
#pragma unroll
    for (int z = 1; z < 4; ++z) {
        float4 v = *(const float4*)(part + (size_t)z * (BATCH * FEATSZ) + idx);
        s.x += v.x; s.y += v.y; s.z += v.z; s.w += v.w;
    }
    *(float4*)(out + idx) = s;
}

extern "C" void kernel_launch(void* const* d_in, const int* in_sizes, int n_in,
                              void* d_out, int out_size, void* d_ws, size_t ws_size,
                              hipStream_t stream) {
    const float* feats = (const float*)d_in[0];
    const float* key   = (const float*)d_in[1];
    const float* wh_w  = (const float*)d_in[2];
    const float* wh_b  = (const float*)d_in[3];
    const float* wv_w  = (const float*)d_in[4];
    const float* wv_b  = (const float*)d_in[5];
    const float* wa_w  = (const float*)d_in[6];

    float* out_att   = (float*)d_out;                 // 64*2048
    float* out_alpha = out_att + BATCH * FEATSZ;      // 64*512

    char* ws = (char*)d_ws;
    float* h            = (float*)(ws);               // 128 KB
    float* scores       = (float*)(ws + 131072);      // 128 KB
    unsigned short* wvb = (unsigned short*)(ws + 262144);  // 2 MB
    float* part         = (float*)(ws + 262144);      // 2 MB (reuses wvb after K1)

    hipLaunchKernelGGL(k_h,        dim3(8, 64),    dim3(256), 0, stream, key, wh_w, wh_b, h);
    hipLaunchKernelGGL(k_wvcvt,    dim3(4096),     dim3(256), 0, stream, wv_w, wvb);
    hipLaunchKernelGGL(k_scores,   dim3(256),      dim3(512), 0, stream, feats, wvb, h, wv_b, wa_w, scores);
    hipLaunchKernelGGL(k_softmax,  dim3(64),       dim3(512), 0, stream, scores, out_alpha);
    hipLaunchKernelGGL(k_att_part, dim3(64, 2, 4), dim3(256), 0, stream, feats, out_alpha, part);
    hipLaunchKernelGGL(k_att_red,  dim3(128),      dim3(256), 0, stream, part, out_att);
}